// Round 1
// baseline (4419.701 us; speedup 1.0000x reference)
//
#include <hip/hip_runtime.h>
#include <cstdint>

#define EPS 1e-5f
typedef float f32x4 __attribute__((ext_vector_type(4)));
typedef short bf8 __attribute__((ext_vector_type(8)));   // 8 bf16 vals (4 VGPRs)
typedef unsigned short u16;
typedef unsigned short u16x8 __attribute__((ext_vector_type(8)));
typedef unsigned int uint4v __attribute__((ext_vector_type(4)));

__device__ __forceinline__ u16 f2b(float f){
  unsigned x = __float_as_uint(f);
  unsigned r = x + 0x7FFFu + ((x>>16)&1u);   // round-to-nearest-even
  return (u16)(r>>16);
}
__device__ __forceinline__ float b2f(u16 h){ return __uint_as_float(((unsigned)h)<<16); }
// pack two f32 -> one dword of 2 bf16 (a in low half); round-half-up (ties differ from RNE only)
__device__ __forceinline__ unsigned pk2(float a, float b){
  unsigned ua = __float_as_uint(a) + 0x8000u;
  unsigned ub = __float_as_uint(b) + 0x8000u;
  return __builtin_amdgcn_perm(ub, ua, 0x07060302u);
}

#define GLL(gp, lp) __builtin_amdgcn_global_load_lds((__attribute__((address_space(1))) const void*)(gp), (__attribute__((address_space(3))) void*)(lp), 16, 0, 0)

// ---------------------------------------------------------------- K0a: expm + Mhat hi/lo fragment table
__global__ __launch_bounds__(1024) void k_prep(const float* __restrict__ A, const float* __restrict__ dtp,
    const float* __restrict__ stg, const float* __restrict__ stb,
    float* __restrict__ abeta, u16* __restrict__ ft)
{
  __shared__ float M[4096], Ta[4096], Tb[4096], P[4096];
  __shared__ float cmn[64];
  int tid = threadIdx.x;
  float dt = dtp[0];
  for (int e=tid; e<4096; e+=1024){
    float v = dt * A[e];
    int i = e>>6, j = e&63;
    M[e] = v;
    P[e] = v + (i==j ? 1.0f : 0.0f);
    Ta[e] = v;
  }
  __syncthreads();
  float* src = Ta; float* dst = Tb;
  for (int k=2;k<=14;k++){
    float inv = 1.0f/(float)k;
    int i = tid>>4, j0 = (tid&15)*4;
    float a0=0,a1=0,a2=0,a3=0;
    for (int m2=0;m2<64;m2++){
      float f = src[i*64+m2];
      const float* Mr = &M[m2*64+j0];
      a0 += f*Mr[0]; a1 += f*Mr[1]; a2 += f*Mr[2]; a3 += f*Mr[3];
    }
    a0*=inv; a1*=inv; a2*=inv; a3*=inv;
    int base=i*64+j0;
    dst[base+0]=a0; dst[base+1]=a1; dst[base+2]=a2; dst[base+3]=a3;
    P[base+0]+=a0; P[base+1]+=a1; P[base+2]+=a2; P[base+3]+=a3;
    __syncthreads();
    float* tmp=src; src=dst; dst=tmp;
  }
  if (tid<64){
    float c0=0, ab=0; int p = tid;
    for (int q2=0;q2<64;q2++){ float ap = P[q2*64+p]; c0 += stg[q2]*ap; ab += stb[q2]*ap; }
    cmn[p] = c0*(1.0f/64.0f);
    abeta[p] = ab;
  }
  __syncthreads();
  for (int e=tid; e<4096; e+=1024){
    int q2=e>>6, p=e&63;
    Ta[e] = stg[q2]*P[q2*64+p] - cmn[p];
  }
  __syncthreads();
  // fragment table: A-operand of MFMA (W2[p][q] = Mhat[q][p]), hi/lo bf16 split (systematic
  // weight-quantization error pumps near-unit modes of A_bar coherently -> must be ~fp32).
  for (int ii=0; ii<4; ii++){
    int e = tid*4+ii;
    int j = e&7, l = (e>>3)&63, kt=(e>>9)&1, mt=e>>10;
    int q2 = 16*(2*kt + (j>>2)) + 4*(l>>4) + (j&3);
    int p = 16*mt + (l&15);
    float v = Ta[q2*64+p];
    u16 hi = f2b(v);
    float lo = v - b2f(hi);
    ft[e] = hi;
    ft[e+4096] = f2b(lo);
  }
}

// ---------------------------------------------------------------- K0b: weights -> bf16
__global__ __launch_bounds__(256) void k_wcvt(const float* __restrict__ gw, const float* __restrict__ bw,
   const float* __restrict__ cw, const float* __restrict__ dw,
   u16* __restrict__ ogw, u16* __restrict__ obw, u16* __restrict__ ocw, u16* __restrict__ odw)
{
  int n = blockIdx.x*256 + threadIdx.x;
  if (n < 2097152) ogw[n] = f2b(gw[n]);
  else if (n < 2162688) obw[n-2097152] = f2b(bw[n-2097152]);
  else if (n < 2228224) ocw[n-2162688] = f2b(cw[n-2162688]);
  else odw[n-2228224] = f2b(dw[n-2228224]);
}

// ---------------------------------------------------------------- K1: layernorm + depthwise conv + residual -> bf16
__global__ __launch_bounds__(256) void k_lnconv(const float* __restrict__ x, const float* __restrict__ gin,
  const float* __restrict__ bin, const float* __restrict__ cwt, const float* __restrict__ cb, u16* __restrict__ xn)
{
  __shared__ float red[10][8];
  int tid = threadIdx.x; int w = tid>>6; int lane = tid&63;
  int r0 = blockIdx.x*8;
  int bt = r0>>12, t0 = r0&4095;
  int c4 = tid*4;
  f32x4 g4 = *(const f32x4*)(gin + c4);
  f32x4 b4 = *(const f32x4*)(bin + c4);
  f32x4 vals[10];
  for (int lr=0; lr<10; lr++){
    int t = t0 - 1 + lr;
    f32x4 xv = {0,0,0,0};
    bool ok = (t>=0 && t<4096);
    if (ok) xv = *(const f32x4*)(x + (size_t)(bt*4096+t)*1024 + c4);
    float s = xv.x+xv.y+xv.z+xv.w;
    float q = xv.x*xv.x+xv.y*xv.y+xv.z*xv.z+xv.w*xv.w;
    for (int m2=1;m2<=32;m2<<=1){ s += __shfl_xor(s,m2,64); q += __shfl_xor(q,m2,64); }
    if (lane==0){ red[lr][w]=s; red[lr][4+w]=q; }
    __syncthreads();
    s = red[lr][0]+red[lr][1]+red[lr][2]+red[lr][3];
    q = red[lr][4]+red[lr][5]+red[lr][6]+red[lr][7];
    float mu = s*(1.f/1024.f);
    float var = q*(1.f/1024.f) - mu*mu;
    float rr = rsqrtf(var + EPS);
    f32x4 o = {0,0,0,0};
    if (ok){
      o.x=(xv.x-mu)*rr*g4.x+b4.x; o.y=(xv.y-mu)*rr*g4.y+b4.y;
      o.z=(xv.z-mu)*rr*g4.z+b4.z; o.w=(xv.w-mu)*rr*g4.w+b4.w;
    }
    vals[lr]=o;
  }
  float w0[4], w1[4], w2[4], cbv[4];
  for (int ii=0;ii<4;ii++){ int c = c4+ii; w0[ii]=cwt[c*3+0]; w1[ii]=cwt[c*3+1]; w2[ii]=cwt[c*3+2]; cbv[ii]=cb[c]; }
  for (int lr=1; lr<=8; lr++){
    int t = t0 + lr - 1;
    f32x4 o;
    o.x = vals[lr].x + w0[0]*vals[lr-1].x + w1[0]*vals[lr].x + w2[0]*vals[lr+1].x + cbv[0];
    o.y = vals[lr].y + w0[1]*vals[lr-1].y + w1[1]*vals[lr].y + w2[1]*vals[lr+1].y + cbv[1];
    o.z = vals[lr].z + w0[2]*vals[lr-1].z + w1[2]*vals[lr].z + w2[2]*vals[lr+1].z + cbv[2];
    o.w = vals[lr].w + w0[3]*vals[lr-1].w + w1[3]*vals[lr].w + w2[3]*vals[lr+1].w + cbv[3];
    size_t off = (size_t)(bt*4096+t)*1024 + c4;
    unsigned lo2 = (unsigned)f2b(o.x) | ((unsigned)f2b(o.y)<<16);
    unsigned hi2 = (unsigned)f2b(o.z) | ((unsigned)f2b(o.w)<<16);
    uint2 pk; pk.x=lo2; pk.y=hi2;
    *(uint2*)(xn + off) = pk;
  }
}

// ---------------------------------------------------------------- K2: gate GEMM + sigmoid + xg
__global__ __launch_bounds__(256) void k_gate(const u16* __restrict__ xn, const u16* __restrict__ gw,
    const float* __restrict__ gb, u16* __restrict__ gate_o, u16* __restrict__ xg_o)
{
  __shared__ u16 As[128*32], Bs[128*32];
  int tid=threadIdx.x, w=tid>>6, l=tid&63;
  int n0 = blockIdx.x*128, m0 = blockIdx.y*128;
  int wr = w>>1, wc = w&1;
  f32x4 acc[4][4] = {};
  for (int kk=0; kk<32; kk++){
    int k0 = kk*32;
    for (int i2=0;i2<2;i2++){
      const char* ga = (const char*)xn + ((size_t)(m0+32*w+16*i2+(l>>2))*1024 + k0)*2 + (l&3)*16;
      GLL(ga, (char*)As + (32*w+16*i2)*64);
      const char* gbp = (const char*)gw + ((size_t)(n0+32*w+16*i2+(l>>2))*1024 + k0)*2 + (l&3)*16;
      GLL(gbp, (char*)Bs + (32*w+16*i2)*64);
    }
    __syncthreads();
    bf8 af[4], bfr[4];
    for (int mt=0;mt<4;mt++) af[mt] = *(const bf8*)(As + (wr*64+mt*16+(l&15))*32 + 8*(l>>4));
    for (int nt=0;nt<4;nt++) bfr[nt] = *(const bf8*)(Bs + (wc*64+nt*16+(l&15))*32 + 8*(l>>4));
    for (int mt=0;mt<4;mt++) for (int nt=0;nt<4;nt++)
      acc[mt][nt] = __builtin_amdgcn_mfma_f32_16x16x32_bf16(af[mt], bfr[nt], acc[mt][nt], 0,0,0);
    __syncthreads();
  }
  int g = l>>4, c = l&15;
  for (int nt=0;nt<4;nt++){
    int n = n0 + wc*64 + nt*16 + c;
    float bias = gb[n];
    for (int mt=0;mt<4;mt++){
      for (int r=0;r<4;r++){
        int row = m0 + wr*64 + mt*16 + 4*g + r;
        float v = acc[mt][nt][r] + bias;
        float sg = 1.0f/(1.0f + __expf(-v));
        if (n < 1024){
          gate_o[(size_t)row*1024 + n] = f2b(sg);
        } else {
          float xv = b2f(xn[(size_t)row*1024 + (n-1024)]);
          xg_o[(size_t)row*1024 + (n-1024)] = f2b(xv*sg);
        }
      }
    }
  }
}

// ---------------------------------------------------------------- K3: Bm (-> c_ws, scan layout) and Cm (bf16)
__global__ __launch_bounds__(256) void k_bc(const u16* __restrict__ xg, const u16* __restrict__ xn,
   const u16* __restrict__ bw, const u16* __restrict__ cw,
   const float* __restrict__ bb, const float* __restrict__ cbias_, const float* __restrict__ abeta,
   float* __restrict__ c_ws, u16* __restrict__ cm)
{
  __shared__ u16 As[128*32], Bs[64*32];
  int tid=threadIdx.x, w=tid>>6, l=tid&63;
  int id = blockIdx.x; int half = id>>7; int m0 = (id&127)*128;
  const u16* Ap = half ? xn : xg;
  const u16* Bp = half ? cw : bw;
  f32x4 acc[2][4]={};
  for (int kk=0;kk<32;kk++){
    int k0=kk*32;
    for (int i2=0;i2<2;i2++){
      const char* ga=(const char*)Ap + ((size_t)(m0+32*w+16*i2+(l>>2))*1024+k0)*2+(l&3)*16;
      GLL(ga, (char*)As+(32*w+16*i2)*64);
    }
    { const char* gbp=(const char*)Bp + ((size_t)(16*w+(l>>2))*1024+k0)*2+(l&3)*16;
      GLL(gbp, (char*)Bs+(16*w)*64); }
    __syncthreads();
    bf8 af[2], bfr[4];
    for (int mt=0;mt<2;mt++) af[mt]=*(const bf8*)(As+(32*w+16*mt+(l&15))*32+8*(l>>4));
    for (int nt=0;nt<4;nt++) bfr[nt]=*(const bf8*)(Bs+(16*nt+(l&15))*32+8*(l>>4));
    for (int mt=0;mt<2;mt++) for(int nt=0;nt<4;nt++)
      acc[mt][nt]=__builtin_amdgcn_mfma_f32_16x16x32_bf16(af[mt],bfr[nt],acc[mt][nt],0,0,0);
    __syncthreads();
  }
  int g=l>>4, c=l&15;
  if (half==0){
    for (int nt=0;nt<4;nt++){ int n=16*nt+c; float bias=bb[n]; float ab=abeta[n];
      for(int mt=0;mt<2;mt++) for(int r=0;r<4;r++){
        int row=m0+32*w+16*mt+4*g+r; int bt=row>>12, t=row&4095;
        float v=acc[mt][nt][r]+bias + (t>0?ab:0.0f);
        c_ws[(size_t)t*256 + bt*64 + n] = v;
      }
    }
  } else {
    for (int nt=0;nt<4;nt++){ int n=16*nt+c; float bias=cbias_[n];
      for(int mt=0;mt<2;mt++) for(int r=0;r<4;r++){
        int row=m0+32*w+16*mt+4*g+r;
        cm[(size_t)row*64+n]=f2b(acc[mt][nt][r]+bias);
      }
    }
  }
}

// ---------------------------------------------------------------- K4: sequential scan — one wave, all 4 batches.
// z_{t+1} = Mhat^T·bf16(r_t·z_t) + c_{t+1}; Mhat hi+lo bf16.
// R3 restructure: 16 INDEPENDENT MFMAs (4 acc groups hA/hB/lA/lB) + VALU combine tree.
// Kills the 4-deep dependent-MFMA chain (in-order issue stalled ~3x L_mfma per step).
// Same products, fp32 reassociation only; identical vm-op counts preserve vmcnt(24) proof.
__global__ __launch_bounds__(64,1) void k_scan(const float* __restrict__ c_ws, const u16* __restrict__ ft,
  float* __restrict__ z_ws)
{
  __shared__ float ring[16*256];   // 16 slots x 1024 B
  int l=threadIdx.x, g=l>>4, b=(l&15)&3;
  const bf8* ftv=(const bf8*)ft;
  bf8 Wh[4][2], Wl[4][2];
  for(int mt=0;mt<4;mt++)for(int kt=0;kt<2;kt++){
    Wh[mt][kt]=ftv[(mt*2+kt)*64+l];
    Wl[mt][kt]=ftv[(8+mt*2+kt)*64+l];
  }
  const f32x4 zed = {0.f,0.f,0.f,0.f};
  f32x4 z0,z1,z2,z3;
  {
    const float* zp = c_ws + b*64 + 4*g;   // t=0: z_0 = c_0 (K3 omitted abeta at t==0)
    z0=*(const f32x4*)(zp+0); z1=*(const f32x4*)(zp+16); z2=*(const f32x4*)(zp+32); z3=*(const f32x4*)(zp+48);
  }
  for(int u2=1;u2<=8;u2++){
    const char* ga=(const char*)c_ws + (size_t)u2*1024 + l*16;
    GLL(ga, (char*)ring + u2*1024);
  }
  asm volatile("s_waitcnt vmcnt(0)" ::: "memory");
  unsigned laneoff;
  {
    __attribute__((address_space(3))) float* l3=( __attribute__((address_space(3))) float*)ring;
    laneoff=(unsigned)(uintptr_t)l3 + (unsigned)(b*256 + g*16);
  }
  f32x4 cA0,cA1,cA2,cA3, cB0,cB1,cB2,cB3;
  {
    unsigned ro = laneoff + 1024u;   // slot 1 = c_1
    asm volatile("ds_read_b128 %0, %4 offset:0\n\t"
                 "ds_read_b128 %1, %4 offset:64\n\t"
                 "ds_read_b128 %2, %4 offset:128\n\t"
                 "ds_read_b128 %3, %4 offset:192\n\t"
                 "s_waitcnt lgkmcnt(0)"
                 : "=v"(cA0),"=v"(cA1),"=v"(cA2),"=v"(cA3) : "v"(ro) : "memory");
  }
  // z store layout (fp32, R1): z_ws[t*1024 + col*64 + 16*mt + 4*g + r], col=l&15
  unsigned voff = (unsigned)(((l&15)*64 + 4*g)*4);
  unsigned long long zb = (unsigned long long)(uintptr_t)z_ws;
  bf8 zf0, zf1;

// reduce z -> rr, pack a=z*rr -> zf0/zf1, store z at voff (then voff += 4096)
#define FINISH() do { \
  f32x4 s4=(z0+z1)+(z2+z3); \
  float s=(s4.x+s4.y)+(s4.z+s4.w); \
  f32x4 qa=z0*z0; qa=z1*z1+qa; \
  f32x4 qb=z2*z2; qb=z3*z3+qb; \
  f32x4 q4=qa+qb; \
  float q=(q4.x+q4.y)+(q4.z+q4.w); \
  float sB=s, qB=q; \
  asm("v_permlane16_swap_b32 %0, %1" : "+v"(s), "+v"(sB)); \
  asm("v_permlane16_swap_b32 %0, %1" : "+v"(q), "+v"(qB)); \
  s+=sB; q+=qB; \
  float sC=s, qC=q; \
  asm("v_permlane32_swap_b32 %0, %1" : "+v"(s), "+v"(sC)); \
  asm("v_permlane32_swap_b32 %0, %1" : "+v"(q), "+v"(qC)); \
  s+=sC; q+=qC; \
  float mu=s*(1.f/64.f); \
  float var=q*(1.f/64.f)-mu*mu; \
  float rr=rsqrtf(var+EPS); \
  f32x4 a0=z0*rr, a1=z1*rr, a2=z2*rr, a3=z3*rr; \
  uint4v p0, p1; \
  p0.x=pk2(a0.x,a0.y); p0.y=pk2(a0.z,a0.w); p0.z=pk2(a1.x,a1.y); p0.w=pk2(a1.z,a1.w); \
  p1.x=pk2(a2.x,a2.y); p1.y=pk2(a2.z,a2.w); p1.z=pk2(a3.x,a3.y); p1.w=pk2(a3.z,a3.w); \
  { union { uint4v u; bf8 h; } cv; cv.u=p0; zf0=cv.h; cv.u=p1; zf1=cv.h; } \
  asm volatile("global_store_dwordx4 %0, %1, %5\n\t" \
               "global_store_dwordx4 %0, %2, %5 offset:64\n\t" \
               "global_store_dwordx4 %0, %3, %5 offset:128\n\t" \
               "global_store_dwordx4 %0, %4, %5 offset:192" \
               :: "v"(voff), "v"(z0), "v"(z1), "v"(z2), "v"(z3), "s"(zb) : "memory"); \
  voff += 4096u; \
} while(0)

  // prologue: normalize/pack/store z_0 (no MFMA yet)
  FINISH();

// STEP T: z_{T+1} = W·a_T + c_{T+1} via 16 independent MFMAs, then FINISH (reduce/pack/store),
// then vmcnt(24) -> ds_read c_{T+2} -> GLL slot T+9.
// vm ops per step: 4 stores + 1 GLL (stores precede the vmcnt wait) -> the GLL for slot (T+2)
// (issued step T-7) has 34 newer vm-ops at the wait; 24 <= 34 -> safe (unchanged arithmetic).
#define STEP(T, CR0,CR1,CR2,CR3, CN0,CN1,CN2,CN3) do { \
  asm volatile("s_waitcnt lgkmcnt(0)" : "+v"(CR0),"+v"(CR1),"+v"(CR2),"+v"(CR3) :: "memory"); \
  f32x4 hA0=__builtin_amdgcn_mfma_f32_16x16x32_bf16(Wh[0][0],zf0,CR0,0,0,0); \
  f32x4 hA1=__builtin_amdgcn_mfma_f32_16x16x32_bf16(Wh[1][0],zf0,CR1,0,0,0); \
  f32x4 hA2=__builtin_amdgcn_mfma_f32_16x16x32_bf16(Wh[2][0],zf0,CR2,0,0,0); \
  f32x4 hA3=__builtin_amdgcn_mfma_f32_16x16x32_bf16(Wh[3][0],zf0,CR3,0,0,0); \
  f32x4 hB0=__builtin_amdgcn_mfma_f32_16x16x32_bf16(Wh[0][1],zf1,zed,0,0,0); \
  f32x4 hB1=__builtin_amdgcn_mfma_f32_16x16x32_bf16(Wh[1][1],zf1,zed,0,0,0); \
  f32x4 hB2=__builtin_amdgcn_mfma_f32_16x16x32_bf16(Wh[2][1],zf1,zed,0,0,0); \
  f32x4 hB3=__builtin_amdgcn_mfma_f32_16x16x32_bf16(Wh[3][1],zf1,zed,0,0,0); \
  f32x4 lA0=__builtin_amdgcn_mfma_f32_16x16x32_bf16(Wl[0][0],zf0,zed,0,0,0); \
  f32x4 lA1=__builtin_amdgcn_mfma_f32_16x16x32_bf16(Wl[1][0],zf0,zed,0,0,0); \
  f32x4 lA2=__builtin_amdgcn_mfma_f32_16x16x32_bf16(Wl[2][0],zf0,zed,0,0,0); \
  f32x4 lA3=__builtin_amdgcn_mfma_f32_16x16x32_bf16(Wl[3][0],zf0,zed,0,0,0); \
  f32x4 lB0=__builtin_amdgcn_mfma_f32_16x16x32_bf16(Wl[0][1],zf1,zed,0,0,0); \
  f32x4 lB1=__builtin_amdgcn_mfma_f32_16x16x32_bf16(Wl[1][1],zf1,zed,0,0,0); \
  f32x4 lB2=__builtin_amdgcn_mfma_f32_16x16x32_bf16(Wl[2][1],zf1,zed,0,0,0); \
  f32x4 lB3=__builtin_amdgcn_mfma_f32_16x16x32_bf16(Wl[3][1],zf1,zed,0,0,0); \
  z0=(hA0+hB0)+(lA0+lB0); \
  z1=(hA1+hB1)+(lA1+lB1); \
  z2=(hA2+hB2)+(lA2+lB2); \
  z3=(hA3+hB3)+(lA3+lB3); \
  FINISH(); \
  asm volatile("s_waitcnt vmcnt(24)" ::: "memory"); \
  { unsigned ro2 = laneoff + ((unsigned)(((T)+2)&15))*1024u; \
    asm volatile("ds_read_b128 %0, %4 offset:0\n\t" \
                 "ds_read_b128 %1, %4 offset:64\n\t" \
                 "ds_read_b128 %2, %4 offset:128\n\t" \
                 "ds_read_b128 %3, %4 offset:192" \
                 : "=v"(CN0),"=v"(CN1),"=v"(CN2),"=v"(CN3) : "v"(ro2) : "memory"); } \
  { const char* ga2=(const char*)c_ws + (size_t)((T)+9)*1024 + l*16; \
    GLL(ga2, (char*)ring + (((T)+9)&15)*1024); } \
} while(0)

  for (int t=0; t<4096; t+=2){
    STEP(t,   cA0,cA1,cA2,cA3, cB0,cB1,cB2,cB3);
    STEP(t+1, cB0,cB1,cB2,cB3, cA0,cA1,cA2,cA3);
  }
#undef STEP
#undef FINISH
}

// ---------------------------------------------------------------- K4b: y_t = Cm_t * LN(z_t)  (parallel over tokens)
__global__ __launch_bounds__(256) void k_y(const float* __restrict__ z_ws, const u16* __restrict__ cm,
  const float* __restrict__ stg, const float* __restrict__ stb, u16* __restrict__ y)
{
  int tid=threadIdx.x, w=tid>>6, l=tid&63;
  int token = blockIdx.x*4 + w;
  int bt = token>>12, t = token&4095;
  float zv = z_ws[(size_t)t*1024 + bt*64 + l];
  float s=zv, q=zv*zv;
  for (int m2=1;m2<=32;m2<<=1){ s += __shfl_xor(s,m2,64); q += __shfl_xor(q,m2,64); }
  float mu=s*(1.f/64.f), var=q*(1.f/64.f)-mu*mu, rr=rsqrtf(var+EPS);
  float sv=(zv-mu)*rr*stg[l]+stb[l];
  y[(size_t)token*64 + l] = f2b(sv * b2f(cm[(size_t)token*64+l]));
}

// ---------------------------------------------------------------- K5: out = (y @ D_w^T + D_b) * gate
__global__ __launch_bounds__(256) void k_out(const u16* __restrict__ y, const u16* __restrict__ dw,
   const float* __restrict__ db, const u16* __restrict__ gate, float* __restrict__ out)
{
  __shared__ float tr[4][16][68];
  int tid=threadIdx.x, w=tid>>6, l=tid&63, g=l>>4, c=l&15;
  int n0=blockIdx.x*64, m0=blockIdx.y*64;
  int mrow = m0 + 16*w + c;
  bf8 af0=*(const bf8*)(y + (size_t)mrow*64 + 8*g);
  bf8 af1=*(const bf8*)(y + (size_t)mrow*64 + 32 + 8*g);
  f32x4 acc[4];
  for(int nt=0;nt<4;nt++){
    int n=n0+16*nt+c;
    bf8 b0=*(const bf8*)(dw + (size_t)n*64 + 8*g);
    bf8 b1=*(const bf8*)(dw + (size_t)n*64 + 32 + 8*g);
    f32x4 a={0,0,0,0};
    a=__builtin_amdgcn_mfma_f32_16x16x32_bf16(af0,b0,a,0,0,0);
    a=__builtin_amdgcn_mfma_f32_16x16x32_bf16(af1,b1,a,0,0,0);
    acc[nt]=a+db[n];
  }
  for(int nt=0;nt<4;nt++) for(int r=0;r<4;r++) tr[w][4*g+r][16*nt+c]=acc[nt][r];
  __syncthreads();
  int lr=l>>2, cc0=(l&3)*16;
  int grow=m0+16*w+lr;
  const u16* gp = gate + (size_t)grow*1024 + n0 + cc0;
  u16x8 g0=*(const u16x8*)(gp), g1=*(const u16x8*)(gp+8);
  float* op = out + (size_t)grow*1024 + n0 + cc0;
  float vv[16];
  for(int j2=0;j2<16;j2++){
    u16 gb16 = (j2<8)? g0[j2] : g1[j2-8];
    vv[j2]=tr[w][lr][cc0+j2]*b2f(gb16);
  }
  for(int j2=0;j2<4;j2++){
    f32x4 ov={vv[4*j2],vv[4*j2+1],vv[4*j2+2],vv[4*j2+3]};
    *(f32x4*)(op+4*j2)=ov;
  }
}

// ----------------------------------------------------------------
extern "C" void kernel_launch(void* const* d_in, const int* in_sizes, int n_in,
                              void* d_out, int out_size, void* d_ws, size_t ws_size,
                              hipStream_t stream) {
  const float* x=(const float*)d_in[0];
  const float* A=(const float*)d_in[1];
  const float* dt=(const float*)d_in[2];
  const float* B_w=(const float*)d_in[3];
  const float* B_b=(const float*)d_in[4];
  const float* C_w=(const float*)d_in[5];
  const float* C_b=(const float*)d_in[6];
  const float* D_w=(const float*)d_in[7];
  const float* D_b=(const float*)d_in[8];
  const float* conv_w=(const float*)d_in[9];
  const float* conv_b=(const float*)d_in[10];
  const float* gate_w=(const float*)d_in[11];
  const float* gate_b=(const float*)d_in[12];
  const float* ln_in_g=(const float*)d_in[13];
  const float* ln_in_b=(const float*)d_in[14];
  const float* ln_st_g=(const float*)d_in[15];
  const float* ln_st_b=(const float*)d_in[16];
  char* ws=(char*)d_ws;
  u16* xn   =(u16*)(ws);                    // 33,554,432
  u16* xg   =(u16*)(ws+33554432);           // 33,554,432
  u16* gate =(u16*)(ws+67108864);           // 33,554,432
  u16* gwb  =(u16*)(ws+100663296);          // 4,194,304
  u16* bwb  =(u16*)(ws+104857600);          // 131,072
  u16* cwb  =(u16*)(ws+104988672);          // 131,072
  u16* dwb  =(u16*)(ws+105119744);          // 131,072
  u16* cm   =(u16*)(ws+105250816);          // 2,097,152
  float* c_ws=(float*)(ws+107347968);       // 4112*1024B = 4,210,688
  float* z_ws=(float*)(ws+111558656);       // 16,777,216 (fp32 z)
  u16* y    =(u16*)(ws+128335872);          // 2,097,152
  float* abeta=(float*)(ws+130433024);      // 256
  u16* ft   =(u16*)(ws+130433280);          // 16,384
  float* out=(float*)d_out;

  hipLaunchKernelGGL(k_prep,  dim3(1),      dim3(1024),0,stream, A, dt, ln_st_g, ln_st_b, abeta, ft);
  hipLaunchKernelGGL(k_wcvt,  dim3(8960),   dim3(256), 0,stream, gate_w,B_w,C_w,D_w, gwb,bwb,cwb,dwb);
  hipLaunchKernelGGL(k_lnconv,dim3(2048),   dim3(256), 0,stream, x, ln_in_g, ln_in_b, conv_w, conv_b, xn);
  hipLaunchKernelGGL(k_gate,  dim3(16,128), dim3(256), 0,stream, xn,gwb,gate_b,gate,xg);
  hipLaunchKernelGGL(k_bc,    dim3(256),    dim3(256), 0,stream, xg,xn,bwb,cwb,B_b,C_b,abeta,c_ws,cm);
  hipLaunchKernelGGL(k_scan,  dim3(1),      dim3(64),  0,stream, c_ws, ft, z_ws);
  hipLaunchKernelGGL(k_y,     dim3(4096),   dim3(256), 0,stream, z_ws,cm,ln_st_g,ln_st_b,y);
  hipLaunchKernelGGL(k_out,   dim3(16,256), dim3(256), 0,stream, y,dwb,D_b,gate,out);
}

// Round 3
// 2990.613 us; speedup vs baseline: 1.4779x; 1.4779x over previous
//
#include <hip/hip_runtime.h>
#include <cstdint>

#define EPS 1e-5f
typedef float f32x4 __attribute__((ext_vector_type(4)));
typedef short bf8 __attribute__((ext_vector_type(8)));   // 8 bf16 vals (4 VGPRs)
typedef unsigned short u16;
typedef unsigned short u16x8 __attribute__((ext_vector_type(8)));
typedef unsigned int uint4v __attribute__((ext_vector_type(4)));

__device__ __forceinline__ u16 f2b(float f){
  unsigned x = __float_as_uint(f);
  unsigned r = x + 0x7FFFu + ((x>>16)&1u);   // round-to-nearest-even
  return (u16)(r>>16);
}
__device__ __forceinline__ float b2f(u16 h){ return __uint_as_float(((unsigned)h)<<16); }
// pack two f32 -> one dword of 2 bf16 (a in low half); round-half-up (ties differ from RNE only)
__device__ __forceinline__ unsigned pk2(float a, float b){
  unsigned ua = __float_as_uint(a) + 0x8000u;
  unsigned ub = __float_as_uint(b) + 0x8000u;
  return __builtin_amdgcn_perm(ub, ua, 0x07060302u);
}

#define GLL(gp, lp) __builtin_amdgcn_global_load_lds((__attribute__((address_space(1))) const void*)(gp), (__attribute__((address_space(3))) void*)(lp), 16, 0, 0)

// ---------------------------------------------------------------- K0a: expm + Mhat hi/lo fragment table
__global__ __launch_bounds__(1024) void k_prep(const float* __restrict__ A, const float* __restrict__ dtp,
    const float* __restrict__ stg, const float* __restrict__ stb,
    float* __restrict__ abeta, u16* __restrict__ ft)
{
  __shared__ float M[4096], Ta[4096], Tb[4096], P[4096];
  __shared__ float cmn[64];
  int tid = threadIdx.x;
  float dt = dtp[0];
  for (int e=tid; e<4096; e+=1024){
    float v = dt * A[e];
    int i = e>>6, j = e&63;
    M[e] = v;
    P[e] = v + (i==j ? 1.0f : 0.0f);
    Ta[e] = v;
  }
  __syncthreads();
  float* src = Ta; float* dst = Tb;
  for (int k=2;k<=14;k++){
    float inv = 1.0f/(float)k;
    int i = tid>>4, j0 = (tid&15)*4;
    float a0=0,a1=0,a2=0,a3=0;
    for (int m2=0;m2<64;m2++){
      float f = src[i*64+m2];
      const float* Mr = &M[m2*64+j0];
      a0 += f*Mr[0]; a1 += f*Mr[1]; a2 += f*Mr[2]; a3 += f*Mr[3];
    }
    a0*=inv; a1*=inv; a2*=inv; a3*=inv;
    int base=i*64+j0;
    dst[base+0]=a0; dst[base+1]=a1; dst[base+2]=a2; dst[base+3]=a3;
    P[base+0]+=a0; P[base+1]+=a1; P[base+2]+=a2; P[base+3]+=a3;
    __syncthreads();
    float* tmp=src; src=dst; dst=tmp;
  }
  if (tid<64){
    float c0=0, ab=0; int p = tid;
    for (int q2=0;q2<64;q2++){ float ap = P[q2*64+p]; c0 += stg[q2]*ap; ab += stb[q2]*ap; }
    cmn[p] = c0*(1.0f/64.0f);
    abeta[p] = ab;
  }
  __syncthreads();
  for (int e=tid; e<4096; e+=1024){
    int q2=e>>6, p=e&63;
    Ta[e] = stg[q2]*P[q2*64+p] - cmn[p];
  }
  __syncthreads();
  // fragment table: A-operand of MFMA (W2[p][q] = Mhat[q][p]), hi/lo bf16 split (systematic
  // weight-quantization error pumps near-unit modes of A_bar coherently -> must be ~fp32).
  for (int ii=0; ii<4; ii++){
    int e = tid*4+ii;
    int j = e&7, l = (e>>3)&63, kt=(e>>9)&1, mt=e>>10;
    int q2 = 16*(2*kt + (j>>2)) + 4*(l>>4) + (j&3);
    int p = 16*mt + (l&15);
    float v = Ta[q2*64+p];
    u16 hi = f2b(v);
    float lo = v - b2f(hi);
    ft[e] = hi;
    ft[e+4096] = f2b(lo);
  }
}

// ---------------------------------------------------------------- K0b: weights -> bf16
__global__ __launch_bounds__(256) void k_wcvt(const float* __restrict__ gw, const float* __restrict__ bw,
   const float* __restrict__ cw, const float* __restrict__ dw,
   u16* __restrict__ ogw, u16* __restrict__ obw, u16* __restrict__ ocw, u16* __restrict__ odw)
{
  int n = blockIdx.x*256 + threadIdx.x;
  if (n < 2097152) ogw[n] = f2b(gw[n]);
  else if (n < 2162688) obw[n-2097152] = f2b(bw[n-2097152]);
  else if (n < 2228224) ocw[n-2162688] = f2b(cw[n-2162688]);
  else odw[n-2228224] = f2b(dw[n-2228224]);
}

// ---------------------------------------------------------------- K1: layernorm + depthwise conv + residual -> bf16
__global__ __launch_bounds__(256) void k_lnconv(const float* __restrict__ x, const float* __restrict__ gin,
  const float* __restrict__ bin, const float* __restrict__ cwt, const float* __restrict__ cb, u16* __restrict__ xn)
{
  __shared__ float red[10][8];
  int tid = threadIdx.x; int w = tid>>6; int lane = tid&63;
  int r0 = blockIdx.x*8;
  int bt = r0>>12, t0 = r0&4095;
  int c4 = tid*4;
  f32x4 g4 = *(const f32x4*)(gin + c4);
  f32x4 b4 = *(const f32x4*)(bin + c4);
  f32x4 vals[10];
  for (int lr=0; lr<10; lr++){
    int t = t0 - 1 + lr;
    f32x4 xv = {0,0,0,0};
    bool ok = (t>=0 && t<4096);
    if (ok) xv = *(const f32x4*)(x + (size_t)(bt*4096+t)*1024 + c4);
    float s = xv.x+xv.y+xv.z+xv.w;
    float q = xv.x*xv.x+xv.y*xv.y+xv.z*xv.z+xv.w*xv.w;
    for (int m2=1;m2<=32;m2<<=1){ s += __shfl_xor(s,m2,64); q += __shfl_xor(q,m2,64); }
    if (lane==0){ red[lr][w]=s; red[lr][4+w]=q; }
    __syncthreads();
    s = red[lr][0]+red[lr][1]+red[lr][2]+red[lr][3];
    q = red[lr][4]+red[lr][5]+red[lr][6]+red[lr][7];
    float mu = s*(1.f/1024.f);
    float var = q*(1.f/1024.f) - mu*mu;
    float rr = rsqrtf(var + EPS);
    f32x4 o = {0,0,0,0};
    if (ok){
      o.x=(xv.x-mu)*rr*g4.x+b4.x; o.y=(xv.y-mu)*rr*g4.y+b4.y;
      o.z=(xv.z-mu)*rr*g4.z+b4.z; o.w=(xv.w-mu)*rr*g4.w+b4.w;
    }
    vals[lr]=o;
  }
  float w0[4], w1[4], w2[4], cbv[4];
  for (int ii=0;ii<4;ii++){ int c = c4+ii; w0[ii]=cwt[c*3+0]; w1[ii]=cwt[c*3+1]; w2[ii]=cwt[c*3+2]; cbv[ii]=cb[c]; }
  for (int lr=1; lr<=8; lr++){
    int t = t0 + lr - 1;
    f32x4 o;
    o.x = vals[lr].x + w0[0]*vals[lr-1].x + w1[0]*vals[lr].x + w2[0]*vals[lr+1].x + cbv[0];
    o.y = vals[lr].y + w0[1]*vals[lr-1].y + w1[1]*vals[lr].y + w2[1]*vals[lr+1].y + cbv[1];
    o.z = vals[lr].z + w0[2]*vals[lr-1].z + w1[2]*vals[lr].z + w2[2]*vals[lr+1].z + cbv[2];
    o.w = vals[lr].w + w0[3]*vals[lr-1].w + w1[3]*vals[lr].w + w2[3]*vals[lr+1].w + cbv[3];
    size_t off = (size_t)(bt*4096+t)*1024 + c4;
    unsigned lo2 = (unsigned)f2b(o.x) | ((unsigned)f2b(o.y)<<16);
    unsigned hi2 = (unsigned)f2b(o.z) | ((unsigned)f2b(o.w)<<16);
    uint2 pk; pk.x=lo2; pk.y=hi2;
    *(uint2*)(xn + off) = pk;
  }
}

// ---------------------------------------------------------------- K2: gate GEMM + sigmoid + xg
__global__ __launch_bounds__(256) void k_gate(const u16* __restrict__ xn, const u16* __restrict__ gw,
    const float* __restrict__ gb, u16* __restrict__ gate_o, u16* __restrict__ xg_o)
{
  __shared__ u16 As[128*32], Bs[128*32];
  int tid=threadIdx.x, w=tid>>6, l=tid&63;
  int n0 = blockIdx.x*128, m0 = blockIdx.y*128;
  int wr = w>>1, wc = w&1;
  f32x4 acc[4][4] = {};
  for (int kk=0; kk<32; kk++){
    int k0 = kk*32;
    for (int i2=0;i2<2;i2++){
      const char* ga = (const char*)xn + ((size_t)(m0+32*w+16*i2+(l>>2))*1024 + k0)*2 + (l&3)*16;
      GLL(ga, (char*)As + (32*w+16*i2)*64);
      const char* gbp = (const char*)gw + ((size_t)(n0+32*w+16*i2+(l>>2))*1024 + k0)*2 + (l&3)*16;
      GLL(gbp, (char*)Bs + (32*w+16*i2)*64);
    }
    __syncthreads();
    bf8 af[4], bfr[4];
    for (int mt=0;mt<4;mt++) af[mt] = *(const bf8*)(As + (wr*64+mt*16+(l&15))*32 + 8*(l>>4));
    for (int nt=0;nt<4;nt++) bfr[nt] = *(const bf8*)(Bs + (wc*64+nt*16+(l&15))*32 + 8*(l>>4));
    for (int mt=0;mt<4;mt++) for (int nt=0;nt<4;nt++)
      acc[mt][nt] = __builtin_amdgcn_mfma_f32_16x16x32_bf16(af[mt], bfr[nt], acc[mt][nt], 0,0,0);
    __syncthreads();
  }
  int g = l>>4, c = l&15;
  for (int nt=0;nt<4;nt++){
    int n = n0 + wc*64 + nt*16 + c;
    float bias = gb[n];
    for (int mt=0;mt<4;mt++){
      for (int r=0;r<4;r++){
        int row = m0 + wr*64 + mt*16 + 4*g + r;
        float v = acc[mt][nt][r] + bias;
        float sg = 1.0f/(1.0f + __expf(-v));
        if (n < 1024){
          gate_o[(size_t)row*1024 + n] = f2b(sg);
        } else {
          float xv = b2f(xn[(size_t)row*1024 + (n-1024)]);
          xg_o[(size_t)row*1024 + (n-1024)] = f2b(xv*sg);
        }
      }
    }
  }
}

// ---------------------------------------------------------------- K3: Bm (-> c_ws, scan layout) and Cm (bf16)
__global__ __launch_bounds__(256) void k_bc(const u16* __restrict__ xg, const u16* __restrict__ xn,
   const u16* __restrict__ bw, const u16* __restrict__ cw,
   const float* __restrict__ bb, const float* __restrict__ cbias_, const float* __restrict__ abeta,
   float* __restrict__ c_ws, u16* __restrict__ cm)
{
  __shared__ u16 As[128*32], Bs[64*32];
  int tid=threadIdx.x, w=tid>>6, l=tid&63;
  int id = blockIdx.x; int half = id>>7; int m0 = (id&127)*128;
  const u16* Ap = half ? xn : xg;
  const u16* Bp = half ? cw : bw;
  f32x4 acc[2][4]={};
  for (int kk=0;kk<32;kk++){
    int k0=kk*32;
    for (int i2=0;i2<2;i2++){
      const char* ga=(const char*)Ap + ((size_t)(m0+32*w+16*i2+(l>>2))*1024+k0)*2+(l&3)*16;
      GLL(ga, (char*)As+(32*w+16*i2)*64);
    }
    { const char* gbp=(const char*)Bp + ((size_t)(16*w+(l>>2))*1024+k0)*2+(l&3)*16;
      GLL(gbp, (char*)Bs+(16*w)*64); }
    __syncthreads();
    bf8 af[2], bfr[4];
    for (int mt=0;mt<2;mt++) af[mt]=*(const bf8*)(As+(32*w+16*mt+(l&15))*32+8*(l>>4));
    for (int nt=0;nt<4;nt++) bfr[nt]=*(const bf8*)(Bs+(16*nt+(l&15))*32+8*(l>>4));
    for (int mt=0;mt<2;mt++) for(int nt=0;nt<4;nt++)
      acc[mt][nt]=__builtin_amdgcn_mfma_f32_16x16x32_bf16(af[mt],bfr[nt],acc[mt][nt],0,0,0);
    __syncthreads();
  }
  int g=l>>4, c=l&15;
  if (half==0){
    for (int nt=0;nt<4;nt++){ int n=16*nt+c; float bias=bb[n]; float ab=abeta[n];
      for(int mt=0;mt<2;mt++) for(int r=0;r<4;r++){
        int row=m0+32*w+16*mt+4*g+r; int bt=row>>12, t=row&4095;
        float v=acc[mt][nt][r]+bias + (t>0?ab:0.0f);
        c_ws[(size_t)t*256 + bt*64 + n] = v;
      }
    }
  } else {
    for (int nt=0;nt<4;nt++){ int n=16*nt+c; float bias=cbias_[n];
      for(int mt=0;mt<2;mt++) for(int r=0;r<4;r++){
        int row=m0+32*w+16*mt+4*g+r;
        cm[(size_t)row*64+n]=f2b(acc[mt][nt][r]+bias);
      }
    }
  }
}

// ---------------------------------------------------------------- K4: sequential scan — one wave, all 4 batches.
// R5 = R4 with the store off-by-one fixed (R4 double-stored z_0 and shifted all slots by 1).
// Commuted-scalar recurrence: rr_t is a per-batch SCALAR, so
//   z_{t+1} = Mhat^T·(rr_t·z_t) + c  ==  rr_t·(Mhat^T·bf16(z_t)) + c.
// Pack RAW z (bf16 is scale-invariant -> same quantization error), start the R1-proven
// 4-chain/depth-4 MFMA structure immediately; the LN reduce (tree+permlanes+rsqrt, ~100cy)
// runs in PARALLEL with the chain latency instead of serially before it. rr applied in the
// final fma z = u*rr + c. ds_read of c hoisted to step START (~120cy LDS latency hidden
// under the whole step body).
__global__ __launch_bounds__(64,1) void k_scan(const float* __restrict__ c_ws, const u16* __restrict__ ft,
  float* __restrict__ z_ws)
{
  __shared__ float ring[16*256];   // 16 slots x 1024 B
  int l=threadIdx.x, g=l>>4, b=l&3;
  const bf8* ftv=(const bf8*)ft;
  bf8 Wh[4][2], Wl[4][2];
  for(int mt=0;mt<4;mt++)for(int kt=0;kt<2;kt++){
    Wh[mt][kt]=ftv[(mt*2+kt)*64+l];
    Wl[mt][kt]=ftv[(8+mt*2+kt)*64+l];
  }
  const f32x4 zed = {0.f,0.f,0.f,0.f};
  f32x4 z0,z1,z2,z3;
  {
    const float* zp = c_ws + b*64 + 4*g;   // t=0: z_0 = c_0 (K3 omitted abeta at t==0)
    z0=*(const f32x4*)(zp+0); z1=*(const f32x4*)(zp+16); z2=*(const f32x4*)(zp+32); z3=*(const f32x4*)(zp+48);
  }
  for(int u2=1;u2<=8;u2++){
    const char* ga=(const char*)c_ws + (size_t)u2*1024 + l*16;
    GLL(ga, (char*)ring + u2*1024);
  }
  asm volatile("s_waitcnt vmcnt(0)" ::: "memory");
  unsigned laneoff;
  {
    __attribute__((address_space(3))) float* l3=( __attribute__((address_space(3))) float*)ring;
    laneoff=(unsigned)(uintptr_t)l3 + (unsigned)(b*256 + g*16);
  }
  // z store layout (fp32): z_ws[t*1024 + col*64 + 16*mt + 4*g + r], col=l&15
  unsigned voff = (unsigned)(((l&15)*64 + 4*g)*4);
  unsigned long long zb = (unsigned long long)(uintptr_t)z_ws;
  f32x4 cN0,cN1,cN2,cN3;
  bf8 zf0, zf1;

  // ---- prologue: pack zf_0 = bf16(z_0) (RAW, unnormalized). NO store here —
  // step t's phase 4 stores z_t at slot t (voff starts at slot 0).
  {
    uint4v p0,p1;
    p0.x=pk2(z0.x,z0.y); p0.y=pk2(z0.z,z0.w); p0.z=pk2(z1.x,z1.y); p0.w=pk2(z1.z,z1.w);
    p1.x=pk2(z2.x,z2.y); p1.y=pk2(z2.z,z2.w); p1.z=pk2(z3.x,z3.y); p1.w=pk2(z3.z,z3.w);
    { union { uint4v u; bf8 h; } cv; cv.u=p0; zf0=cv.h; cv.u=p1; zf1=cv.h; }
  }

  unsigned slotr = 1024u;          // ring byte offset of slot (t+1)&15 (t=0 -> slot 1)
  unsigned ldst  = 9u*1024u;       // ring byte offset of slot (t+9)&15 (t=0 -> slot 9)
  const char* gsrc = (const char*)c_ws + (size_t)9*1024;   // token t+9

  // per-step vm ops: 1 GLL then 4 stores. GLL for the slot read at step t was issued at
  // step t-8 with 39 newer vm-ops at this wait -> vmcnt(24) <= 39 -> safe.
  for (int t=0; t<4096; ++t){
    // ---- phase 1: prefetches (latency hidden by whole step body)
    asm volatile("s_waitcnt vmcnt(24)" ::: "memory");
    { unsigned ro = laneoff + slotr;
      asm volatile("ds_read_b128 %0, %4 offset:0\n\t"
                   "ds_read_b128 %1, %4 offset:64\n\t"
                   "ds_read_b128 %2, %4 offset:128\n\t"
                   "ds_read_b128 %3, %4 offset:192"
                   : "=v"(cN0),"=v"(cN1),"=v"(cN2),"=v"(cN3) : "v"(ro) : "memory"); }
    GLL(gsrc + (size_t)l*16, (char*)ring + ldst);
    // ---- phase 2: u = W·zf, 4 independent chains of depth 4 (R1-proven shape, acc init 0)
    f32x4 u0=__builtin_amdgcn_mfma_f32_16x16x32_bf16(Wh[0][0],zf0,zed,0,0,0);
    f32x4 u1=__builtin_amdgcn_mfma_f32_16x16x32_bf16(Wh[1][0],zf0,zed,0,0,0);
    f32x4 u2=__builtin_amdgcn_mfma_f32_16x16x32_bf16(Wh[2][0],zf0,zed,0,0,0);
    f32x4 u3=__builtin_amdgcn_mfma_f32_16x16x32_bf16(Wh[3][0],zf0,zed,0,0,0);
    u0=__builtin_amdgcn_mfma_f32_16x16x32_bf16(Wh[0][1],zf1,u0,0,0,0);
    u1=__builtin_amdgcn_mfma_f32_16x16x32_bf16(Wh[1][1],zf1,u1,0,0,0);
    u2=__builtin_amdgcn_mfma_f32_16x16x32_bf16(Wh[2][1],zf1,u2,0,0,0);
    u3=__builtin_amdgcn_mfma_f32_16x16x32_bf16(Wh[3][1],zf1,u3,0,0,0);
    u0=__builtin_amdgcn_mfma_f32_16x16x32_bf16(Wl[0][0],zf0,u0,0,0,0);
    u1=__builtin_amdgcn_mfma_f32_16x16x32_bf16(Wl[1][0],zf0,u1,0,0,0);
    u2=__builtin_amdgcn_mfma_f32_16x16x32_bf16(Wl[2][0],zf0,u2,0,0,0);
    u3=__builtin_amdgcn_mfma_f32_16x16x32_bf16(Wl[3][0],zf0,u3,0,0,0);
    u0=__builtin_amdgcn_mfma_f32_16x16x32_bf16(Wl[0][1],zf1,u0,0,0,0);
    u1=__builtin_amdgcn_mfma_f32_16x16x32_bf16(Wl[1][1],zf1,u1,0,0,0);
    u2=__builtin_amdgcn_mfma_f32_16x16x32_bf16(Wl[2][1],zf1,u2,0,0,0);
    u3=__builtin_amdgcn_mfma_f32_16x16x32_bf16(Wl[3][1],zf1,u3,0,0,0);
    // ---- phase 3: LN reduce of current z -> rr (overlaps MFMA chain latency)
    float rr;
    {
      f32x4 s4=(z0+z1)+(z2+z3);
      float s=(s4.x+s4.y)+(s4.z+s4.w);
      f32x4 qa=z0*z0; qa=z1*z1+qa;
      f32x4 qb=z2*z2; qb=z3*z3+qb;
      f32x4 q4=qa+qb;
      float q=(q4.x+q4.y)+(q4.z+q4.w);
      float sB=s, qB=q;
      asm("v_permlane16_swap_b32 %0, %1" : "+v"(s), "+v"(sB));
      asm("v_permlane16_swap_b32 %0, %1" : "+v"(q), "+v"(qB));
      s+=sB; q+=qB;
      float sC=s, qC=q;
      asm("v_permlane32_swap_b32 %0, %1" : "+v"(s), "+v"(sC));
      asm("v_permlane32_swap_b32 %0, %1" : "+v"(q), "+v"(qC));
      s+=sC; q+=qC;
      float mu=s*(1.f/64.f);
      float var=q*(1.f/64.f)-mu*mu;
      rr=rsqrtf(var+EPS);
    }
    // ---- phase 4: store current z_t at slot t (fire-and-forget)
    asm volatile("global_store_dwordx4 %0, %1, %5\n\t"
                 "global_store_dwordx4 %0, %2, %5 offset:64\n\t"
                 "global_store_dwordx4 %0, %3, %5 offset:128\n\t"
                 "global_store_dwordx4 %0, %4, %5 offset:192"
                 :: "v"(voff), "v"(z0), "v"(z1), "v"(z2), "v"(z3), "s"(zb) : "memory");
    voff += 4096u;
    // ---- phase 5: pointer/slot updates (off critical path)
    slotr = (slotr + 1024u) & 16383u;
    ldst  = (ldst  + 1024u) & 16383u;
    gsrc += 1024;
    // ---- phase 6: z' = u*rr + c  (rr commuted out of the matmul)
    asm volatile("s_waitcnt lgkmcnt(0)" : "+v"(cN0),"+v"(cN1),"+v"(cN2),"+v"(cN3) :: "memory");
    z0 = u0*rr + cN0;
    z1 = u1*rr + cN1;
    z2 = u2*rr + cN2;
    z3 = u3*rr + cN3;
    // ---- phase 7: pack zf = bf16(z') raw
    uint4v p0,p1;
    p0.x=pk2(z0.x,z0.y); p0.y=pk2(z0.z,z0.w); p0.z=pk2(z1.x,z1.y); p0.w=pk2(z1.z,z1.w);
    p1.x=pk2(z2.x,z2.y); p1.y=pk2(z2.z,z2.w); p1.z=pk2(z3.x,z3.y); p1.w=pk2(z3.z,z3.w);
    { union { uint4v u; bf8 h; } cv; cv.u=p0; zf0=cv.h; cv.u=p1; zf1=cv.h; }
  }
  // final iteration (t=4095) stores z_4095 (last in-bounds slot); z_4096 is computed into
  // registers but never stored. GLL prefetches reach token 4104 < 4112 (c_ws padding).
}

// ---------------------------------------------------------------- K4b: y_t = Cm_t * LN(z_t)  (parallel over tokens)
__global__ __launch_bounds__(256) void k_y(const float* __restrict__ z_ws, const u16* __restrict__ cm,
  const float* __restrict__ stg, const float* __restrict__ stb, u16* __restrict__ y)
{
  int tid=threadIdx.x, w=tid>>6, l=tid&63;
  int token = blockIdx.x*4 + w;
  int bt = token>>12, t = token&4095;
  float zv = z_ws[(size_t)t*1024 + bt*64 + l];
  float s=zv, q=zv*zv;
  for (int m2=1;m2<=32;m2<<=1){ s += __shfl_xor(s,m2,64); q += __shfl_xor(q,m2,64); }
  float mu=s*(1.f/64.f), var=q*(1.f/64.f)-mu*mu, rr=rsqrtf(var+EPS);
  float sv=(zv-mu)*rr*stg[l]+stb[l];
  y[(size_t)token*64 + l] = f2b(sv * b2f(cm[(size_t)token*64+l]));
}

// ---------------------------------------------------------------- K5: out = (y @ D_w^T + D_b) * gate
__global__ __launch_bounds__(256) void k_out(const u16* __restrict__ y, const u16* __restrict__ dw,
   const float* __restrict__ db, const u16* __restrict__ gate, float* __restrict__ out)
{
  __shared__ float tr[4][16][68];
  int tid=threadIdx.x, w=tid>>6, l=tid&63, g=l>>4, c=l&15;
  int n0=blockIdx.x*64, m0=blockIdx.y*64;
  int mrow = m0 + 16*w + c;
  bf8 af0=*(const bf8*)(y + (size_t)mrow*64 + 8*g);
  bf8 af1=*(const bf8*)(y + (size_t)mrow*64 + 32 + 8*g);
  f32x4 acc[4];
  for(int nt=0;nt<4;nt++){
    int n=n0+16*nt+c;
    bf8 b0=*(const bf8*)(dw + (size_t)n*64 + 8*g);
    bf8 b1=*(const bf8*)(dw + (size_t)n*64 + 32 + 8*g);
    f32x4 a={0,0,0,0};
    a=__builtin_amdgcn_mfma_f32_16x16x32_bf16(af0,b0,a,0,0,0);
    a=__builtin_amdgcn_mfma_f32_16x16x32_bf16(af1,b1,a,0,0,0);
    acc[nt]=a+db[n];
  }
  for(int nt=0;nt<4;nt++) for(int r=0;r<4;r++) tr[w][4*g+r][16*nt+c]=acc[nt][r];
  __syncthreads();
  int lr=l>>2, cc0=(l&3)*16;
  int grow=m0+16*w+lr;
  const u16* gp = gate + (size_t)grow*1024 + n0 + cc0;
  u16x8 g0=*(const u16x8*)(gp), g1=*(const u16x8*)(gp+8);
  float* op = out + (size_t)grow*1024 + n0 + cc0;
  float vv[16];
  for(int j2=0;j2<16;j2++){
    u16 gb16 = (j2<8)? g0[j2] : g1[j2-8];
    vv[j2]=tr[w][lr][cc0+j2]*b2f(gb16);
  }
  for(int j2=0;j2<4;j2++){
    f32x4 ov={vv[4*j2],vv[4*j2+1],vv[4*j2+2],vv[4*j2+3]};
    *(f32x4*)(op+4*j2)=ov;
  }
}

// ----------------------------------------------------------------
extern "C" void kernel_launch(void* const* d_in, const int* in_sizes, int n_in,
                              void* d_out, int out_size, void* d_ws, size_t ws_size,
                              hipStream_t stream) {
  const float* x=(const float*)d_in[0];
  const float* A=(const float*)d_in[1];
  const float* dt=(const float*)d_in[2];
  const float* B_w=(const float*)d_in[3];
  const float* B_b=(const float*)d_in[4];
  const float* C_w=(const float*)d_in[5];
  const float* C_b=(const float*)d_in[6];
  const float* D_w=(const float*)d_in[7];
  const float* D_b=(const float*)d_in[8];
  const float* conv_w=(const float*)d_in[9];
  const float* conv_b=(const float*)d_in[10];
  const float* gate_w=(const float*)d_in[11];
  const float* gate_b=(const float*)d_in[12];
  const float* ln_in_g=(const float*)d_in[13];
  const float* ln_in_b=(const float*)d_in[14];
  const float* ln_st_g=(const float*)d_in[15];
  const float* ln_st_b=(const float*)d_in[16];
  char* ws=(char*)d_ws;
  u16* xn   =(u16*)(ws);                    // 33,554,432
  u16* xg   =(u16*)(ws+33554432);           // 33,554,432
  u16* gate =(u16*)(ws+67108864);           // 33,554,432
  u16* gwb  =(u16*)(ws+100663296);          // 4,194,304
  u16* bwb  =(u16*)(ws+104857600);          // 131,072
  u16* cwb  =(u16*)(ws+104988672);          // 131,072
  u16* dwb  =(u16*)(ws+105119744);          // 131,072
  u16* cm   =(u16*)(ws+105250816);          // 2,097,152
  float* c_ws=(float*)(ws+107347968);       // 4112*1024B = 4,210,688
  float* z_ws=(float*)(ws+111558656);       // 16,777,216 (fp32 z)
  u16* y    =(u16*)(ws+128335872);          // 2,097,152
  float* abeta=(float*)(ws+130433024);      // 256
  u16* ft   =(u16*)(ws+130433280);          // 16,384
  float* out=(float*)d_out;

  hipLaunchKernelGGL(k_prep,  dim3(1),      dim3(1024),0,stream, A, dt, ln_st_g, ln_st_b, abeta, ft);
  hipLaunchKernelGGL(k_wcvt,  dim3(8960),   dim3(256), 0,stream, gate_w,B_w,C_w,D_w, gwb,bwb,cwb,dwb);
  hipLaunchKernelGGL(k_lnconv,dim3(2048),   dim3(256), 0,stream, x, ln_in_g, ln_in_b, conv_w, conv_b, xn);
  hipLaunchKernelGGL(k_gate,  dim3(16,128), dim3(256), 0,stream, xn,gwb,gate_b,gate,xg);
  hipLaunchKernelGGL(k_bc,    dim3(256),    dim3(256), 0,stream, xg,xn,bwb,cwb,B_b,C_b,abeta,c_ws,cm);
  hipLaunchKernelGGL(k_scan,  dim3(1),      dim3(64),  0,stream, c_ws, ft, z_ws);
  hipLaunchKernelGGL(k_y,     dim3(4096),   dim3(256), 0,stream, z_ws,cm,ln_st_g,ln_st_b,y);
  hipLaunchKernelGGL(k_out,   dim3(16,256), dim3(256), 0,stream, y,dwb,D_b,gate,out);
}

// Round 4
// 1718.197 us; speedup vs baseline: 2.5723x; 1.7406x over previous
//
#include <hip/hip_runtime.h>
#include <cstdint>

#define EPS 1e-5f
typedef float f32x4 __attribute__((ext_vector_type(4)));
typedef short bf8 __attribute__((ext_vector_type(8)));   // 8 bf16 vals (4 VGPRs)
typedef unsigned short u16;
typedef unsigned short u16x8 __attribute__((ext_vector_type(8)));
typedef unsigned int uint4v __attribute__((ext_vector_type(4)));

__device__ __forceinline__ u16 f2b(float f){
  unsigned x = __float_as_uint(f);
  unsigned r = x + 0x7FFFu + ((x>>16)&1u);   // round-to-nearest-even
  return (u16)(r>>16);
}
__device__ __forceinline__ float b2f(u16 h){ return __uint_as_float(((unsigned)h)<<16); }
// pack two f32 -> one dword of 2 bf16 (a in low half); round-half-up (ties differ from RNE only)
__device__ __forceinline__ unsigned pk2(float a, float b){
  unsigned ua = __float_as_uint(a) + 0x8000u;
  unsigned ub = __float_as_uint(b) + 0x8000u;
  return __builtin_amdgcn_perm(ub, ua, 0x07060302u);
}

#define GLL(gp, lp) __builtin_amdgcn_global_load_lds((__attribute__((address_space(1))) const void*)(gp), (__attribute__((address_space(3))) void*)(lp), 16, 0, 0)

// ---------------------------------------------------------------- K0a: expm + Mhat hi/lo fragment table
__global__ __launch_bounds__(1024) void k_prep(const float* __restrict__ A, const float* __restrict__ dtp,
    const float* __restrict__ stg, const float* __restrict__ stb,
    float* __restrict__ abeta, u16* __restrict__ ft)
{
  __shared__ float M[4096], Ta[4096], Tb[4096], P[4096];
  __shared__ float cmn[64];
  int tid = threadIdx.x;
  float dt = dtp[0];
  for (int e=tid; e<4096; e+=1024){
    float v = dt * A[e];
    int i = e>>6, j = e&63;
    M[e] = v;
    P[e] = v + (i==j ? 1.0f : 0.0f);
    Ta[e] = v;
  }
  __syncthreads();
  float* src = Ta; float* dst = Tb;
  for (int k=2;k<=14;k++){
    float inv = 1.0f/(float)k;
    int i = tid>>4, j0 = (tid&15)*4;
    float a0=0,a1=0,a2=0,a3=0;
    for (int m2=0;m2<64;m2++){
      float f = src[i*64+m2];
      const float* Mr = &M[m2*64+j0];
      a0 += f*Mr[0]; a1 += f*Mr[1]; a2 += f*Mr[2]; a3 += f*Mr[3];
    }
    a0*=inv; a1*=inv; a2*=inv; a3*=inv;
    int base=i*64+j0;
    dst[base+0]=a0; dst[base+1]=a1; dst[base+2]=a2; dst[base+3]=a3;
    P[base+0]+=a0; P[base+1]+=a1; P[base+2]+=a2; P[base+3]+=a3;
    __syncthreads();
    float* tmp=src; src=dst; dst=tmp;
  }
  if (tid<64){
    float c0=0, ab=0; int p = tid;
    for (int q2=0;q2<64;q2++){ float ap = P[q2*64+p]; c0 += stg[q2]*ap; ab += stb[q2]*ap; }
    cmn[p] = c0*(1.0f/64.0f);
    abeta[p] = ab;
  }
  __syncthreads();
  for (int e=tid; e<4096; e+=1024){
    int q2=e>>6, p=e&63;
    Ta[e] = stg[q2]*P[q2*64+p] - cmn[p];
  }
  __syncthreads();
  // fragment table: A-operand of MFMA (W2[p][q] = Mhat[q][p]), hi/lo bf16 split (systematic
  // weight-quantization error pumps near-unit modes of A_bar coherently -> must be ~fp32).
  for (int ii=0; ii<4; ii++){
    int e = tid*4+ii;
    int j = e&7, l = (e>>3)&63, kt=(e>>9)&1, mt=e>>10;
    int q2 = 16*(2*kt + (j>>2)) + 4*(l>>4) + (j&3);
    int p = 16*mt + (l&15);
    float v = Ta[q2*64+p];
    u16 hi = f2b(v);
    float lo = v - b2f(hi);
    ft[e] = hi;
    ft[e+4096] = f2b(lo);
  }
}

// ---------------------------------------------------------------- K0b: weights -> bf16
__global__ __launch_bounds__(256) void k_wcvt(const float* __restrict__ gw, const float* __restrict__ bw,
   const float* __restrict__ cw, const float* __restrict__ dw,
   u16* __restrict__ ogw, u16* __restrict__ obw, u16* __restrict__ ocw, u16* __restrict__ odw)
{
  int n = blockIdx.x*256 + threadIdx.x;
  if (n < 2097152) ogw[n] = f2b(gw[n]);
  else if (n < 2162688) obw[n-2097152] = f2b(bw[n-2097152]);
  else if (n < 2228224) ocw[n-2162688] = f2b(cw[n-2162688]);
  else odw[n-2228224] = f2b(dw[n-2228224]);
}

// ---------------------------------------------------------------- K1: layernorm + depthwise conv + residual -> bf16
__global__ __launch_bounds__(256) void k_lnconv(const float* __restrict__ x, const float* __restrict__ gin,
  const float* __restrict__ bin, const float* __restrict__ cwt, const float* __restrict__ cb, u16* __restrict__ xn)
{
  __shared__ float red[10][8];
  int tid = threadIdx.x; int w = tid>>6; int lane = tid&63;
  int r0 = blockIdx.x*8;
  int bt = r0>>12, t0 = r0&4095;
  int c4 = tid*4;
  f32x4 g4 = *(const f32x4*)(gin + c4);
  f32x4 b4 = *(const f32x4*)(bin + c4);
  f32x4 vals[10];
  for (int lr=0; lr<10; lr++){
    int t = t0 - 1 + lr;
    f32x4 xv = {0,0,0,0};
    bool ok = (t>=0 && t<4096);
    if (ok) xv = *(const f32x4*)(x + (size_t)(bt*4096+t)*1024 + c4);
    float s = xv.x+xv.y+xv.z+xv.w;
    float q = xv.x*xv.x+xv.y*xv.y+xv.z*xv.z+xv.w*xv.w;
    for (int m2=1;m2<=32;m2<<=1){ s += __shfl_xor(s,m2,64); q += __shfl_xor(q,m2,64); }
    if (lane==0){ red[lr][w]=s; red[lr][4+w]=q; }
    __syncthreads();
    s = red[lr][0]+red[lr][1]+red[lr][2]+red[lr][3];
    q = red[lr][4]+red[lr][5]+red[lr][6]+red[lr][7];
    float mu = s*(1.f/1024.f);
    float var = q*(1.f/1024.f) - mu*mu;
    float rr = rsqrtf(var + EPS);
    f32x4 o = {0,0,0,0};
    if (ok){
      o.x=(xv.x-mu)*rr*g4.x+b4.x; o.y=(xv.y-mu)*rr*g4.y+b4.y;
      o.z=(xv.z-mu)*rr*g4.z+b4.z; o.w=(xv.w-mu)*rr*g4.w+b4.w;
    }
    vals[lr]=o;
  }
  float w0[4], w1[4], w2[4], cbv[4];
  for (int ii=0;ii<4;ii++){ int c = c4+ii; w0[ii]=cwt[c*3+0]; w1[ii]=cwt[c*3+1]; w2[ii]=cwt[c*3+2]; cbv[ii]=cb[c]; }
  for (int lr=1; lr<=8; lr++){
    int t = t0 + lr - 1;
    f32x4 o;
    o.x = vals[lr].x + w0[0]*vals[lr-1].x + w1[0]*vals[lr].x + w2[0]*vals[lr+1].x + cbv[0];
    o.y = vals[lr].y + w0[1]*vals[lr-1].y + w1[1]*vals[lr].y + w2[1]*vals[lr+1].y + cbv[1];
    o.z = vals[lr].z + w0[2]*vals[lr-1].z + w1[2]*vals[lr].z + w2[2]*vals[lr+1].z + cbv[2];
    o.w = vals[lr].w + w0[3]*vals[lr-1].w + w1[3]*vals[lr].w + w2[3]*vals[lr+1].w + cbv[3];
    size_t off = (size_t)(bt*4096+t)*1024 + c4;
    unsigned lo2 = (unsigned)f2b(o.x) | ((unsigned)f2b(o.y)<<16);
    unsigned hi2 = (unsigned)f2b(o.z) | ((unsigned)f2b(o.w)<<16);
    uint2 pk; pk.x=lo2; pk.y=hi2;
    *(uint2*)(xn + off) = pk;
  }
}

// ---------------------------------------------------------------- K2: gate GEMM + sigmoid + xg
// R6: epilogue rebuilt. Old version: 64 scalar u16 stores + 64 scalar u16 xn loads per
// thread, scattered over 64 rows -> partial-128B-line eviction under L2 thrash ->
// WRITE_SIZE 4.4 GB (65x unique), FETCH 2.57 GB; kernel BW-bound at 5.1 TB/s, 1400 us.
// New: (a) XCD-chunk swizzle (each XCD gets contiguous m-panels, n fastest -> B_w stays
// L2-resident); (b) LDS f32 transpose stage (overlaid on As/Bs; two 64-row passes) ->
// each thread owns 64 contiguous output bytes -> dwordx4 stores, whole-line writes;
// (c) xn reads for the xg half vectorized u16x8. Numerics bit-identical.
__global__ __launch_bounds__(256) void k_gate(const u16* __restrict__ xn, const u16* __restrict__ gw,
    const float* __restrict__ gb, u16* __restrict__ gate_o, u16* __restrict__ xg_o)
{
  __shared__ char smem[33792];          // As(8K)+Bs(8K) during K-loop; st(64x132 f32) after
  u16* As = (u16*)smem;
  u16* Bs = (u16*)(smem + 8192);
  float* st = (float*)smem;
  int tid=threadIdx.x, w=tid>>6, l=tid&63;
  // XCD-chunk swizzle: flat dispatch id round-robins XCDs; give XCD k originals
  // [k*256,(k+1)*256) in x-fastest order (16 m-panels x 16 n-blocks per XCD).
  int flat = blockIdx.x + (int)gridDim.x*blockIdx.y;    // 2048 blocks, %8==0
  int logical = (flat&7)*256 + (flat>>3);
  int n0 = (logical&15)*128, m0 = (logical>>4)*128;
  int wr = w>>1, wc = w&1;
  f32x4 acc[4][4] = {};
  for (int kk=0; kk<32; kk++){
    int k0 = kk*32;
    for (int i2=0;i2<2;i2++){
      const char* ga = (const char*)xn + ((size_t)(m0+32*w+16*i2+(l>>2))*1024 + k0)*2 + (l&3)*16;
      GLL(ga, (char*)As + (32*w+16*i2)*64);
      const char* gbp = (const char*)gw + ((size_t)(n0+32*w+16*i2+(l>>2))*1024 + k0)*2 + (l&3)*16;
      GLL(gbp, (char*)Bs + (32*w+16*i2)*64);
    }
    __syncthreads();
    bf8 af[4], bfr[4];
    for (int mt=0;mt<4;mt++) af[mt] = *(const bf8*)(As + (wr*64+mt*16+(l&15))*32 + 8*(l>>4));
    for (int nt=0;nt<4;nt++) bfr[nt] = *(const bf8*)(Bs + (wc*64+nt*16+(l&15))*32 + 8*(l>>4));
    for (int mt=0;mt<4;mt++) for (int nt=0;nt<4;nt++)
      acc[mt][nt] = __builtin_amdgcn_mfma_f32_16x16x32_bf16(af[mt], bfr[nt], acc[mt][nt], 0,0,0);
    __syncthreads();
  }
  // ---- epilogue: two 64-row passes; pass p stages waves wr==p through LDS
  bool isxg = (n0 >= 1024);
  int r2 = tid>>2, q = tid&3;          // r2: row within pass (0..63), q: 32-col quarter
  f32x4 gb4[8];
  for (int j=0;j<8;j++) gb4[j] = *(const f32x4*)(gb + n0 + q*32 + j*4);
  int g = l>>4, c = l&15;
  for (int p=0;p<2;p++){
    __syncthreads();
    if (wr==p){
      for (int mt=0;mt<4;mt++) for (int nt=0;nt<4;nt++)
        for (int r=0;r<4;r++)
          st[(mt*16+4*g+r)*132 + wc*64+nt*16+c] = acc[mt][nt][r];
    }
    __syncthreads();
    int row = m0 + p*64 + r2;
    const float* sp = st + r2*132 + q*32;
    u16 ob[32];
    if (!isxg){
      for (int j=0;j<8;j++){
        f32x4 v = *(const f32x4*)(sp + 4*j);
        v = v + gb4[j];
        ob[4*j+0] = f2b(1.0f/(1.0f+__expf(-v.x)));
        ob[4*j+1] = f2b(1.0f/(1.0f+__expf(-v.y)));
        ob[4*j+2] = f2b(1.0f/(1.0f+__expf(-v.z)));
        ob[4*j+3] = f2b(1.0f/(1.0f+__expf(-v.w)));
      }
    } else {
      const u16* xp = xn + (size_t)row*1024 + (n0-1024) + q*32;
      u16 xb[32];
      for (int j=0;j<4;j++){
        u16x8 t8 = *(const u16x8*)(xp + 8*j);
        for (int e=0;e<8;e++) xb[8*j+e] = t8[e];
      }
      for (int j=0;j<8;j++){
        f32x4 v = *(const f32x4*)(sp + 4*j);
        v = v + gb4[j];
        ob[4*j+0] = f2b(b2f(xb[4*j+0]) * (1.0f/(1.0f+__expf(-v.x))));
        ob[4*j+1] = f2b(b2f(xb[4*j+1]) * (1.0f/(1.0f+__expf(-v.y))));
        ob[4*j+2] = f2b(b2f(xb[4*j+2]) * (1.0f/(1.0f+__expf(-v.z))));
        ob[4*j+3] = f2b(b2f(xb[4*j+3]) * (1.0f/(1.0f+__expf(-v.w))));
      }
    }
    u16* op = isxg ? (xg_o + (size_t)row*1024 + (n0-1024) + q*32)
                   : (gate_o + (size_t)row*1024 + n0 + q*32);
    unsigned od[16];
    for (int i2=0;i2<16;i2++) od[i2] = (unsigned)ob[2*i2] | ((unsigned)ob[2*i2+1]<<16);
    uint4v s0 = {od[0],od[1],od[2],od[3]};
    uint4v s1 = {od[4],od[5],od[6],od[7]};
    uint4v s2 = {od[8],od[9],od[10],od[11]};
    uint4v s3 = {od[12],od[13],od[14],od[15]};
    *(uint4v*)(op+ 0) = s0;
    *(uint4v*)(op+ 8) = s1;
    *(uint4v*)(op+16) = s2;
    *(uint4v*)(op+24) = s3;
  }
}

// ---------------------------------------------------------------- K3: Bm (-> c_ws, scan layout) and Cm (bf16)
__global__ __launch_bounds__(256) void k_bc(const u16* __restrict__ xg, const u16* __restrict__ xn,
   const u16* __restrict__ bw, const u16* __restrict__ cw,
   const float* __restrict__ bb, const float* __restrict__ cbias_, const float* __restrict__ abeta,
   float* __restrict__ c_ws, u16* __restrict__ cm)
{
  __shared__ u16 As[128*32], Bs[64*32];
  int tid=threadIdx.x, w=tid>>6, l=tid&63;
  int id = blockIdx.x; int half = id>>7; int m0 = (id&127)*128;
  const u16* Ap = half ? xn : xg;
  const u16* Bp = half ? cw : bw;
  f32x4 acc[2][4]={};
  for (int kk=0;kk<32;kk++){
    int k0=kk*32;
    for (int i2=0;i2<2;i2++){
      const char* ga=(const char*)Ap + ((size_t)(m0+32*w+16*i2+(l>>2))*1024+k0)*2+(l&3)*16;
      GLL(ga, (char*)As+(32*w+16*i2)*64);
    }
    { const char* gbp=(const char*)Bp + ((size_t)(16*w+(l>>2))*1024+k0)*2+(l&3)*16;
      GLL(gbp, (char*)Bs+(16*w)*64); }
    __syncthreads();
    bf8 af[2], bfr[4];
    for (int mt=0;mt<2;mt++) af[mt]=*(const bf8*)(As+(32*w+16*mt+(l&15))*32+8*(l>>4));
    for (int nt=0;nt<4;nt++) bfr[nt]=*(const bf8*)(Bs+(16*nt+(l&15))*32+8*(l>>4));
    for (int mt=0;mt<2;mt++) for(int nt=0;nt<4;nt++)
      acc[mt][nt]=__builtin_amdgcn_mfma_f32_16x16x32_bf16(af[mt],bfr[nt],acc[mt][nt],0,0,0);
    __syncthreads();
  }
  int g=l>>4, c=l&15;
  if (half==0){
    for (int nt=0;nt<4;nt++){ int n=16*nt+c; float bias=bb[n]; float ab=abeta[n];
      for(int mt=0;mt<2;mt++) for(int r=0;r<4;r++){
        int row=m0+32*w+16*mt+4*g+r; int bt=row>>12, t=row&4095;
        float v=acc[mt][nt][r]+bias + (t>0?ab:0.0f);
        c_ws[(size_t)t*256 + bt*64 + n] = v;
      }
    }
  } else {
    for (int nt=0;nt<4;nt++){ int n=16*nt+c; float bias=cbias_[n];
      for(int mt=0;mt<2;mt++) for(int r=0;r<4;r++){
        int row=m0+32*w+16*mt+4*g+r;
        cm[(size_t)row*64+n]=f2b(acc[mt][nt][r]+bias);
      }
    }
  }
}

// ---------------------------------------------------------------- K4: sequential scan — one wave, all 4 batches.
// R5: commuted-scalar recurrence (rr applied after MFMA), ds_read hoisted to step start.
__global__ __launch_bounds__(64,1) void k_scan(const float* __restrict__ c_ws, const u16* __restrict__ ft,
  float* __restrict__ z_ws)
{
  __shared__ float ring[16*256];   // 16 slots x 1024 B
  int l=threadIdx.x, g=l>>4, b=l&3;
  const bf8* ftv=(const bf8*)ft;
  bf8 Wh[4][2], Wl[4][2];
  for(int mt=0;mt<4;mt++)for(int kt=0;kt<2;kt++){
    Wh[mt][kt]=ftv[(mt*2+kt)*64+l];
    Wl[mt][kt]=ftv[(8+mt*2+kt)*64+l];
  }
  const f32x4 zed = {0.f,0.f,0.f,0.f};
  f32x4 z0,z1,z2,z3;
  {
    const float* zp = c_ws + b*64 + 4*g;   // t=0: z_0 = c_0 (K3 omitted abeta at t==0)
    z0=*(const f32x4*)(zp+0); z1=*(const f32x4*)(zp+16); z2=*(const f32x4*)(zp+32); z3=*(const f32x4*)(zp+48);
  }
  for(int u2=1;u2<=8;u2++){
    const char* ga=(const char*)c_ws + (size_t)u2*1024 + l*16;
    GLL(ga, (char*)ring + u2*1024);
  }
  asm volatile("s_waitcnt vmcnt(0)" ::: "memory");
  unsigned laneoff;
  {
    __attribute__((address_space(3))) float* l3=( __attribute__((address_space(3))) float*)ring;
    laneoff=(unsigned)(uintptr_t)l3 + (unsigned)(b*256 + g*16);
  }
  // z store layout (fp32): z_ws[t*1024 + col*64 + 16*mt + 4*g + r], col=l&15
  unsigned voff = (unsigned)(((l&15)*64 + 4*g)*4);
  unsigned long long zb = (unsigned long long)(uintptr_t)z_ws;
  f32x4 cN0,cN1,cN2,cN3;
  bf8 zf0, zf1;

  // ---- prologue: pack zf_0 = bf16(z_0) (RAW, unnormalized). NO store here —
  // step t's phase 4 stores z_t at slot t (voff starts at slot 0).
  {
    uint4v p0,p1;
    p0.x=pk2(z0.x,z0.y); p0.y=pk2(z0.z,z0.w); p0.z=pk2(z1.x,z1.y); p0.w=pk2(z1.z,z1.w);
    p1.x=pk2(z2.x,z2.y); p1.y=pk2(z2.z,z2.w); p1.z=pk2(z3.x,z3.y); p1.w=pk2(z3.z,z3.w);
    { union { uint4v u; bf8 h; } cv; cv.u=p0; zf0=cv.h; cv.u=p1; zf1=cv.h; }
  }

  unsigned slotr = 1024u;          // ring byte offset of slot (t+1)&15 (t=0 -> slot 1)
  unsigned ldst  = 9u*1024u;       // ring byte offset of slot (t+9)&15 (t=0 -> slot 9)
  const char* gsrc = (const char*)c_ws + (size_t)9*1024;   // token t+9

  // per-step vm ops: 1 GLL then 4 stores. GLL for the slot read at step t was issued at
  // step t-8 with 39 newer vm-ops at this wait -> vmcnt(24) <= 39 -> safe.
  for (int t=0; t<4096; ++t){
    // ---- phase 1: prefetches (latency hidden by whole step body)
    asm volatile("s_waitcnt vmcnt(24)" ::: "memory");
    { unsigned ro = laneoff + slotr;
      asm volatile("ds_read_b128 %0, %4 offset:0\n\t"
                   "ds_read_b128 %1, %4 offset:64\n\t"
                   "ds_read_b128 %2, %4 offset:128\n\t"
                   "ds_read_b128 %3, %4 offset:192"
                   : "=v"(cN0),"=v"(cN1),"=v"(cN2),"=v"(cN3) : "v"(ro) : "memory"); }
    GLL(gsrc + (size_t)l*16, (char*)ring + ldst);
    // ---- phase 2: u = W·zf, 4 independent chains of depth 4 (R1-proven shape, acc init 0)
    f32x4 u0=__builtin_amdgcn_mfma_f32_16x16x32_bf16(Wh[0][0],zf0,zed,0,0,0);
    f32x4 u1=__builtin_amdgcn_mfma_f32_16x16x32_bf16(Wh[1][0],zf0,zed,0,0,0);
    f32x4 u2=__builtin_amdgcn_mfma_f32_16x16x32_bf16(Wh[2][0],zf0,zed,0,0,0);
    f32x4 u3=__builtin_amdgcn_mfma_f32_16x16x32_bf16(Wh[3][0],zf0,zed,0,0,0);
    u0=__builtin_amdgcn_mfma_f32_16x16x32_bf16(Wh[0][1],zf1,u0,0,0,0);
    u1=__builtin_amdgcn_mfma_f32_16x16x32_bf16(Wh[1][1],zf1,u1,0,0,0);
    u2=__builtin_amdgcn_mfma_f32_16x16x32_bf16(Wh[2][1],zf1,u2,0,0,0);
    u3=__builtin_amdgcn_mfma_f32_16x16x32_bf16(Wh[3][1],zf1,u3,0,0,0);
    u0=__builtin_amdgcn_mfma_f32_16x16x32_bf16(Wl[0][0],zf0,u0,0,0,0);
    u1=__builtin_amdgcn_mfma_f32_16x16x32_bf16(Wl[1][0],zf0,u1,0,0,0);
    u2=__builtin_amdgcn_mfma_f32_16x16x32_bf16(Wl[2][0],zf0,u2,0,0,0);
    u3=__builtin_amdgcn_mfma_f32_16x16x32_bf16(Wl[3][0],zf0,u3,0,0,0);
    u0=__builtin_amdgcn_mfma_f32_16x16x32_bf16(Wl[0][1],zf1,u0,0,0,0);
    u1=__builtin_amdgcn_mfma_f32_16x16x32_bf16(Wl[1][1],zf1,u1,0,0,0);
    u2=__builtin_amdgcn_mfma_f32_16x16x32_bf16(Wl[2][1],zf1,u2,0,0,0);
    u3=__builtin_amdgcn_mfma_f32_16x16x32_bf16(Wl[3][1],zf1,u3,0,0,0);
    // ---- phase 3: LN reduce of current z -> rr (overlaps MFMA chain latency)
    float rr;
    {
      f32x4 s4=(z0+z1)+(z2+z3);
      float s=(s4.x+s4.y)+(s4.z+s4.w);
      f32x4 qa=z0*z0; qa=z1*z1+qa;
      f32x4 qb=z2*z2; qb=z3*z3+qb;
      f32x4 q4=qa+qb;
      float q=(q4.x+q4.y)+(q4.z+q4.w);
      float sB=s, qB=q;
      asm("v_permlane16_swap_b32 %0, %1" : "+v"(s), "+v"(sB));
      asm("v_permlane16_swap_b32 %0, %1" : "+v"(q), "+v"(qB));
      s+=sB; q+=qB;
      float sC=s, qC=q;
      asm("v_permlane32_swap_b32 %0, %1" : "+v"(s), "+v"(sC));
      asm("v_permlane32_swap_b32 %0, %1" : "+v"(q), "+v"(qC));
      s+=sC; q+=qC;
      float mu=s*(1.f/64.f);
      float var=q*(1.f/64.f)-mu*mu;
      rr=rsqrtf(var+EPS);
    }
    // ---- phase 4: store current z_t at slot t (fire-and-forget)
    asm volatile("global_store_dwordx4 %0, %1, %5\n\t"
                 "global_store_dwordx4 %0, %2, %5 offset:64\n\t"
                 "global_store_dwordx4 %0, %3, %5 offset:128\n\t"
                 "global_store_dwordx4 %0, %4, %5 offset:192"
                 :: "v"(voff), "v"(z0), "v"(z1), "v"(z2), "v"(z3), "s"(zb) : "memory");
    voff += 4096u;
    // ---- phase 5: pointer/slot updates (off critical path)
    slotr = (slotr + 1024u) & 16383u;
    ldst  = (ldst  + 1024u) & 16383u;
    gsrc += 1024;
    // ---- phase 6: z' = u*rr + c  (rr commuted out of the matmul)
    asm volatile("s_waitcnt lgkmcnt(0)" : "+v"(cN0),"+v"(cN1),"+v"(cN2),"+v"(cN3) :: "memory");
    z0 = u0*rr + cN0;
    z1 = u1*rr + cN1;
    z2 = u2*rr + cN2;
    z3 = u3*rr + cN3;
    // ---- phase 7: pack zf = bf16(z') raw
    uint4v p0,p1;
    p0.x=pk2(z0.x,z0.y); p0.y=pk2(z0.z,z0.w); p0.z=pk2(z1.x,z1.y); p0.w=pk2(z1.z,z1.w);
    p1.x=pk2(z2.x,z2.y); p1.y=pk2(z2.z,z2.w); p1.z=pk2(z3.x,z3.y); p1.w=pk2(z3.z,z3.w);
    { union { uint4v u; bf8 h; } cv; cv.u=p0; zf0=cv.h; cv.u=p1; zf1=cv.h; }
  }
  // final iteration (t=4095) stores z_4095 (last in-bounds slot); z_4096 is computed into
  // registers but never stored. GLL prefetches reach token 4104 < 4112 (c_ws padding).
}

// ---------------------------------------------------------------- K4b: y_t = Cm_t * LN(z_t)  (parallel over tokens)
__global__ __launch_bounds__(256) void k_y(const float* __restrict__ z_ws, const u16* __restrict__ cm,
  const float* __restrict__ stg, const float* __restrict__ stb, u16* __restrict__ y)
{
  int tid=threadIdx.x, w=tid>>6, l=tid&63;
  int token = blockIdx.x*4 + w;
  int bt = token>>12, t = token&4095;
  float zv = z_ws[(size_t)t*1024 + bt*64 + l];
  float s=zv, q=zv*zv;
  for (int m2=1;m2<=32;m2<<=1){ s += __shfl_xor(s,m2,64); q += __shfl_xor(q,m2,64); }
  float mu=s*(1.f/64.f), var=q*(1.f/64.f)-mu*mu, rr=rsqrtf(var+EPS);
  float sv=(zv-mu)*rr*stg[l]+stb[l];
  y[(size_t)token*64 + l] = f2b(sv * b2f(cm[(size_t)token*64+l]));
}

// ---------------------------------------------------------------- K5: out = (y @ D_w^T + D_b) * gate
__global__ __launch_bounds__(256) void k_out(const u16* __restrict__ y, const u16* __restrict__ dw,
   const float* __restrict__ db, const u16* __restrict__ gate, float* __restrict__ out)
{
  __shared__ float tr[4][16][68];
  int tid=threadIdx.x, w=tid>>6, l=tid&63, g=l>>4, c=l&15;
  int n0=blockIdx.x*64, m0=blockIdx.y*64;
  int mrow = m0 + 16*w + c;
  bf8 af0=*(const bf8*)(y + (size_t)mrow*64 + 8*g);
  bf8 af1=*(const bf8*)(y + (size_t)mrow*64 + 32 + 8*g);
  f32x4 acc[4];
  for(int nt=0;nt<4;nt++){
    int n=n0+16*nt+c;
    bf8 b0=*(const bf8*)(dw + (size_t)n*64 + 8*g);
    bf8 b1=*(const bf8*)(dw + (size_t)n*64 + 32 + 8*g);
    f32x4 a={0,0,0,0};
    a=__builtin_amdgcn_mfma_f32_16x16x32_bf16(af0,b0,a,0,0,0);
    a=__builtin_amdgcn_mfma_f32_16x16x32_bf16(af1,b1,a,0,0,0);
    acc[nt]=a+db[n];
  }
  for(int nt=0;nt<4;nt++) for(int r=0;r<4;r++) tr[w][4*g+r][16*nt+c]=acc[nt][r];
  __syncthreads();
  int lr=l>>2, cc0=(l&3)*16;
  int grow=m0+16*w+lr;
  const u16* gp = gate + (size_t)grow*1024 + n0 + cc0;
  u16x8 g0=*(const u16x8*)(gp), g1=*(const u16x8*)(gp+8);
  float* op = out + (size_t)grow*1024 + n0 + cc0;
  float vv[16];
  for(int j2=0;j2<16;j2++){
    u16 gb16 = (j2<8)? g0[j2] : g1[j2-8];
    vv[j2]=tr[w][lr][cc0+j2]*b2f(gb16);
  }
  for(int j2=0;j2<4;j2++){
    f32x4 ov={vv[4*j2],vv[4*j2+1],vv[4*j2+2],vv[4*j2+3]};
    *(f32x4*)(op+4*j2)=ov;
  }
}

// ----------------------------------------------------------------
extern "C" void kernel_launch(void* const* d_in, const int* in_sizes, int n_in,
                              void* d_out, int out_size, void* d_ws, size_t ws_size,
                              hipStream_t stream) {
  const float* x=(const float*)d_in[0];
  const float* A=(const float*)d_in[1];
  const float* dt=(const float*)d_in[2];
  const float* B_w=(const float*)d_in[3];
  const float* B_b=(const float*)d_in[4];
  const float* C_w=(const float*)d_in[5];
  const float* C_b=(const float*)d_in[6];
  const float* D_w=(const float*)d_in[7];
  const float* D_b=(const float*)d_in[8];
  const float* conv_w=(const float*)d_in[9];
  const float* conv_b=(const float*)d_in[10];
  const float* gate_w=(const float*)d_in[11];
  const float* gate_b=(const float*)d_in[12];
  const float* ln_in_g=(const float*)d_in[13];
  const float* ln_in_b=(const float*)d_in[14];
  const float* ln_st_g=(const float*)d_in[15];
  const float* ln_st_b=(const float*)d_in[16];
  char* ws=(char*)d_ws;
  u16* xn   =(u16*)(ws);                    // 33,554,432
  u16* xg   =(u16*)(ws+33554432);           // 33,554,432
  u16* gate =(u16*)(ws+67108864);           // 33,554,432
  u16* gwb  =(u16*)(ws+100663296);          // 4,194,304
  u16* bwb  =(u16*)(ws+104857600);          // 131,072
  u16* cwb  =(u16*)(ws+104988672);          // 131,072
  u16* dwb  =(u16*)(ws+105119744);          // 131,072
  u16* cm   =(u16*)(ws+105250816);          // 2,097,152
  float* c_ws=(float*)(ws+107347968);       // 4112*1024B = 4,210,688
  float* z_ws=(float*)(ws+111558656);       // 16,777,216 (fp32 z)
  u16* y    =(u16*)(ws+128335872);          // 2,097,152
  float* abeta=(float*)(ws+130433024);      // 256
  u16* ft   =(u16*)(ws+130433280);          // 16,384
  float* out=(float*)d_out;

  hipLaunchKernelGGL(k_prep,  dim3(1),      dim3(1024),0,stream, A, dt, ln_st_g, ln_st_b, abeta, ft);
  hipLaunchKernelGGL(k_wcvt,  dim3(8960),   dim3(256), 0,stream, gate_w,B_w,C_w,D_w, gwb,bwb,cwb,dwb);
  hipLaunchKernelGGL(k_lnconv,dim3(2048),   dim3(256), 0,stream, x, ln_in_g, ln_in_b, conv_w, conv_b, xn);
  hipLaunchKernelGGL(k_gate,  dim3(16,128), dim3(256), 0,stream, xn,gwb,gate_b,gate,xg);
  hipLaunchKernelGGL(k_bc,    dim3(256),    dim3(256), 0,stream, xg,xn,bwb,cwb,B_b,C_b,abeta,c_ws,cm);
  hipLaunchKernelGGL(k_scan,  dim3(1),      dim3(64),  0,stream, c_ws, ft, z_ws);
  hipLaunchKernelGGL(k_y,     dim3(4096),   dim3(256), 0,stream, z_ws,cm,ln_st_g,ln_st_b,y);
  hipLaunchKernelGGL(k_out,   dim3(16,256), dim3(256), 0,stream, y,dwb,D_b,gate,out);
}